// Round 7
// baseline (34.678 us; speedup 1.0000x reference)
//
#include <hip/hip_runtime.h>

#define GL  0.891f      /* DISCOUNT*LAMBDA */
#define OMA 0.99f       /* 1 - alpha */
#define AL  0.01f       /* alpha */

// ---------------- workspace layout (floats) ----------------
#define OFF_H 0                 /* Hbuf: T x H = 524288 */
#define OFF_U 524288            /* u: T = 2048 */
#define WS_FLOATS 526336        /* ~2 MB */

// ================= K1: forward (unchanged from R5) =================
// 256 blocks x 512 threads; block owns rows [8b, 8b+8); halves split k (128 each).
// W1 loads: k-batches of 16, double-buffered, batch0 issued before the barrier.
__global__ __launch_bounds__(512, 2) void fwd_kernel(
    const float* __restrict__ xs, const float* __restrict__ W1,
    const float* __restrict__ b1, const float* __restrict__ W2,
    const float* __restrict__ b2,
    float* __restrict__ Hbuf, float* __restrict__ u) {
  const int tid = threadIdx.x;
  const int j = tid & 255;
  const int half = tid >> 8;            // wave-uniform
  const int r0 = blockIdx.x * 8;
  __shared__ __align__(16) float xsl[8 * 260];   // [r][k], padded rows
  __shared__ __align__(16) float red[8][256];

  {  // stage xs[8][256] -> LDS, coalesced float4
    const int row = tid >> 6;
    const int k0 = (tid & 63) * 4;
    float4 v = *reinterpret_cast<const float4*>(&xs[(r0 + row) * 256 + k0]);
    *reinterpret_cast<float4*>(&xsl[row * 260 + k0]) = v;
  }

  const int kb = half * 128;
  float wcur[16], wnxt[16];
#pragma unroll
  for (int kk = 0; kk < 16; ++kk)       // batch 0 in flight before barrier
    wcur[kk] = W1[(kb + kk) * 256 + j];
  __syncthreads();

  float acc[8] = {0.f, 0.f, 0.f, 0.f, 0.f, 0.f, 0.f, 0.f};
#pragma unroll
  for (int b = 0; b < 8; ++b) {
    if (b < 7) {
#pragma unroll
      for (int kk = 0; kk < 16; ++kk)
        wnxt[kk] = W1[(kb + (b + 1) * 16 + kk) * 256 + j];
    }
    const int k = kb + b * 16;
#pragma unroll
    for (int r = 0; r < 8; ++r) {
#pragma unroll
      for (int q = 0; q < 4; ++q) {
        const float4 xv = *reinterpret_cast<const float4*>(&xsl[r * 260 + k + 4 * q]);
        acc[r] = fmaf(xv.x, wcur[4 * q + 0], acc[r]);
        acc[r] = fmaf(xv.y, wcur[4 * q + 1], acc[r]);
        acc[r] = fmaf(xv.z, wcur[4 * q + 2], acc[r]);
        acc[r] = fmaf(xv.w, wcur[4 * q + 3], acc[r]);
      }
    }
#pragma unroll
    for (int kk = 0; kk < 16; ++kk) wcur[kk] = wnxt[kk];
  }

  if (half == 0) {
#pragma unroll
    for (int r = 0; r < 8; ++r) red[r][j] = acc[r];
  }
  __syncthreads();
  if (half == 1) {
    const float bj = b1[j];
    const float w2j = W2[j];
#pragma unroll
    for (int r = 0; r < 8; ++r) {
      const float a = red[r][j] + acc[r] + bj;
      const float h = fmaxf(a, 0.f);
      Hbuf[(r0 + r) * 256 + j] = h;
      red[r][j] = h * w2j;               // same-thread read->write, safe
    }
  }
  __syncthreads();
  for (int s = 128; s >= 1; s >>= 1) {
    if (j < s) {
#pragma unroll
      for (int rr = 0; rr < 4; ++rr)
        red[half * 4 + rr][j] += red[half * 4 + rr][j + s];
    }
    __syncthreads();
  }
  if (half == 0 && j < 8) u[r0 + j] = red[j][0] + b2[0];
}

// ================= K2: scan + DIRECT W1/b1/W2 gradients =================
// 256 blocks x 512 threads. Block = 16x16 W1 tile: dcb = blk>>4 (d0=16*dcb),
// jc = blk&15 (j0=16*jc). Full t-range per block -> writes its W1 tile
// directly (no partials, no reduce kernel). Thread: jj = tid&15 (column),
// tt = tid>>4 (32 t-groups); t = tc + i*32 + tt so a wave's 4 t-rows are
// adjacent (merged 4x64B H segments; broadcast xs reads). H double-buffered
// x8; chunk-0 prefetch issued before the scan to hide LLC latency.
__global__ __launch_bounds__(512, 2) void scan_w1_kernel(
    const float* __restrict__ u, const float* __restrict__ ys,
    const float* __restrict__ xs, const float* __restrict__ Hbuf,
    const float* __restrict__ W2, float* __restrict__ outp) {
  const int tid = threadIdx.x;
  const int blk = blockIdx.x;
  const int dcb = blk >> 4;             // 0..15
  const int jc = blk & 15;              // 0..15
  const int d0 = dcb * 16;
  const int j0 = jc * 16;
  const int jj = tid & 15;
  const int tt = tid >> 4;              // 0..31
  const int lane = tid & 63;
  const int w = tid >> 6;               // 0..7

  __shared__ __align__(16) float c_l[2048];     // 8 KB
  __shared__ float red[8][16][20];              // 10.2 KB (pad 20 vs banks)
  __shared__ float aggA[8], aggB[8], ag2A[8], ag2B[8], wsum[8];

  const float w2j = W2[j0 + jj];

  // ---- prefetch H chunk 0 (hidden under the scan) ----
  float hA[8], hB[8];
#pragma unroll
  for (int i = 0; i < 8; ++i)
    hA[i] = Hbuf[(i * 32 + tt) * 256 + j0 + jj];

  // ---- scan: thread owns t in [4*tid, 4*tid+4) ----
  float e[4], kp[4];
  {
    const float4 u4 = ((const float4*)u)[tid];
    const float uu[4] = {u4.x, u4.y, u4.z, u4.w};
#pragma unroll
    for (int q = 0; q < 2; ++q) {
      const float4 y = ((const float4*)ys)[2 * tid + q];  // g,done,g,done
      const float da = y.x - uu[2 * q];
      const float db = y.z - uu[2 * q + 1];
      e[2 * q] = da * da;
      e[2 * q + 1] = db * db;
      kp[2 * q] = (y.y > 0.5f) ? 0.f : 1.f;
      kp[2 * q + 1] = (y.w > 0.5f) ? 0.f : 1.f;
    }
  }
  float A = 1.f, B = 0.f;
#pragma unroll
  for (int i = 0; i < 4; ++i) {
    const float a = kp[i] * OMA;
    B = fmaf(a, B, kp[i] * (AL * e[i]));
    A *= a;
  }
#pragma unroll
  for (int s = 1; s < 64; s <<= 1) {    // wave inclusive scan
    const float pA = __shfl_up(A, s, 64);
    const float pB = __shfl_up(B, s, 64);
    if (lane >= s) { B = fmaf(A, pB, B); A *= pA; }
  }
  if (lane == 63) { aggA[w] = A; aggB[w] = B; }
  __syncthreads();
  float rin;
  {
    float rw = 0.f;                     // r entering this wave (r0 = 0)
    for (int v = 0; v < w; ++v) rw = fmaf(aggA[v], rw, aggB[v]);
    float lA = __shfl_up(A, 1, 64);
    float lB = __shfl_up(B, 1, 64);
    if (lane == 0) { lA = 1.f; lB = 0.f; }
    rin = fmaf(lA, rw, lB);
  }
  float sig[4];
  {
    float r = rin;
#pragma unroll
    for (int i = 0; i < 4; ++i) {
      sig[i] = e[i] - r;
      const float a = kp[i] * OMA;
      r = fmaf(a, r, kp[i] * (AL * e[i]));
    }
  }
  if (blk == 0 && tid == 511) outp[66049] = sig[3];   // sigmas[-1]

  float A2 = 1.f, B2 = 0.f;
#pragma unroll
  for (int i = 3; i >= 0; --i) {
    const float a = GL * kp[i];
    B2 = fmaf(a, B2, -sig[i]);
    A2 *= a;
  }
#pragma unroll
  for (int s = 1; s < 64; s <<= 1) {    // wave suffix-inclusive scan
    const float nA = __shfl_down(A2, s, 64);
    const float nB = __shfl_down(B2, s, 64);
    if (lane + s < 64) { B2 = fmaf(A2, nB, B2); A2 *= nA; }
  }
  if (lane == 0) { ag2A[w] = A2; ag2B[w] = B2; }
  __syncthreads();
  float cin;
  {
    float cw = 0.f;                     // c entering this wave from the right
    for (int v = 7; v > w; --v) cw = fmaf(ag2A[v], cw, ag2B[v]);
    float lA = __shfl_down(A2, 1, 64);
    float lB = __shfl_down(B2, 1, 64);
    if (lane == 63) { lA = 1.f; lB = 0.f; }
    cin = fmaf(lA, cw, lB);
  }
  float cr[4];
  float cc = cin, csum = 0.f;
#pragma unroll
  for (int i = 3; i >= 0; --i) {
    cc = fmaf(GL * kp[i], cc, -sig[i]);
    cr[i] = cc;
    csum += cc;
  }
  *reinterpret_cast<float4*>(&c_l[4 * tid]) = make_float4(cr[0], cr[1], cr[2], cr[3]);
  if (blk == 0) {
#pragma unroll
    for (int s = 32; s >= 1; s >>= 1) csum += __shfl_xor(csum, s, 64);
    if (lane == 0) wsum[w] = csum;
  }
  __syncthreads();                      // c_l (+ wsum) ready
  if (blk == 0 && tid == 0) {
    float s = 0.f;
#pragma unroll
    for (int v = 0; v < 8; ++v) s += wsum[v];
    outp[66048] = s;                    // total_b2
  }

  // ---- GEMM: acc[d] over all t; H dbuf x8; xs broadcast-merged b128 ----
  float acc[16];
#pragma unroll
  for (int d = 0; d < 16; ++d) acc[d] = 0.f;
  float sb = 0.f, sw = 0.f;
  const bool do_bw = (dcb == 0);

#pragma unroll 1
  for (int cchunk = 0; cchunk < 8; ++cchunk) {
    const int tc = cchunk * 256;
    if (cchunk < 7) {
#pragma unroll
      for (int i = 0; i < 8; ++i)       // next chunk's H, 8 loads in flight
        hB[i] = Hbuf[(tc + 256 + i * 32 + tt) * 256 + j0 + jj];
    }
#pragma unroll
    for (int i = 0; i < 8; ++i) {
      const int t = tc + i * 32 + tt;
      const float ct = c_l[t];          // 4 distinct/wave, broadcast
      const float h = hA[i];
      const float gc = (h > 0.f) ? w2j * ct : 0.f;
      if (do_bw) { sb += gc; sw = fmaf(ct, h, sw); }
      const float* xp = &xs[t * 256 + d0];
      const float4 x0 = *reinterpret_cast<const float4*>(xp);
      const float4 x1 = *reinterpret_cast<const float4*>(xp + 4);
      const float4 x2 = *reinterpret_cast<const float4*>(xp + 8);
      const float4 x3 = *reinterpret_cast<const float4*>(xp + 12);
      acc[0]  = fmaf(gc, x0.x, acc[0]);
      acc[1]  = fmaf(gc, x0.y, acc[1]);
      acc[2]  = fmaf(gc, x0.z, acc[2]);
      acc[3]  = fmaf(gc, x0.w, acc[3]);
      acc[4]  = fmaf(gc, x1.x, acc[4]);
      acc[5]  = fmaf(gc, x1.y, acc[5]);
      acc[6]  = fmaf(gc, x1.z, acc[6]);
      acc[7]  = fmaf(gc, x1.w, acc[7]);
      acc[8]  = fmaf(gc, x2.x, acc[8]);
      acc[9]  = fmaf(gc, x2.y, acc[9]);
      acc[10] = fmaf(gc, x2.z, acc[10]);
      acc[11] = fmaf(gc, x2.w, acc[11]);
      acc[12] = fmaf(gc, x3.x, acc[12]);
      acc[13] = fmaf(gc, x3.y, acc[13]);
      acc[14] = fmaf(gc, x3.z, acc[14]);
      acc[15] = fmaf(gc, x3.w, acc[15]);
    }
#pragma unroll
    for (int i = 0; i < 8; ++i) hA[i] = hB[i];
  }

  // ---- reduce over tt: shfl across ttl (lane bits 4,5), then 8 waves via LDS ----
#pragma unroll
  for (int d = 0; d < 16; ++d) {
    acc[d] += __shfl_xor(acc[d], 16, 64);
    acc[d] += __shfl_xor(acc[d], 32, 64);
  }
  if (do_bw) {
    sb += __shfl_xor(sb, 16, 64); sb += __shfl_xor(sb, 32, 64);
    sw += __shfl_xor(sw, 16, 64); sw += __shfl_xor(sw, 32, 64);
  }
  if (lane < 16) {                      // ttl==0 lanes: lane == jj
#pragma unroll
    for (int d = 0; d < 16; ++d) red[w][lane][d] = acc[d];
    if (do_bw) { red[w][lane][16] = sb; red[w][lane][17] = sw; }
  }
  __syncthreads();
  if (tid < 256) {
    const int oj = tid & 15;
    const int od = tid >> 4;
    float s = 0.f;
#pragma unroll
    for (int v = 0; v < 8; ++v) s += red[v][oj][od];
    outp[(d0 + od) * 256 + j0 + oj] = s;           // total_W1 tile
  } else if (do_bw && tid < 288) {
    const int q = tid - 256;            // 0..31
    const int col = q & 15;
    const int sel = q >> 4;             // 0 -> b1, 1 -> W2
    float s = 0.f;
#pragma unroll
    for (int v = 0; v < 8; ++v) s += red[v][col][16 + sel];
    outp[(sel ? 65792 : 65536) + j0 + col] = s;    // total_b1 / total_W2
  }
}

extern "C" void kernel_launch(void* const* d_in, const int* in_sizes, int n_in,
                              void* d_out, int out_size, void* d_ws, size_t ws_size,
                              hipStream_t stream) {
  const float* xs = (const float*)d_in[0];   // (2048, 256)
  const float* ys = (const float*)d_in[1];   // (2048, 2)
  const float* W1 = (const float*)d_in[2];   // (256, 256)
  const float* b1 = (const float*)d_in[3];   // (256,)
  const float* W2 = (const float*)d_in[4];   // (256, 1)
  const float* b2 = (const float*)d_in[5];   // (1,)
  float* outp = (float*)d_out;               // 66050 floats
  float* ws = (float*)d_ws;

  if (ws_size < (size_t)WS_FLOATS * sizeof(float)) return;  // loud fail

  float* Hbuf = ws + OFF_H;
  float* ubuf = ws + OFF_U;

  fwd_kernel<<<256, 512, 0, stream>>>(xs, W1, b1, W2, b2, Hbuf, ubuf);
  scan_w1_kernel<<<256, 512, 0, stream>>>(ubuf, ys, xs, Hbuf, W2, outp);
}

// Round 8
// 26.792 us; speedup vs baseline: 1.2943x; 1.2943x over previous
//
#include <hip/hip_runtime.h>

#define GL  0.891f      /* DISCOUNT*LAMBDA */
#define OMA 0.99f       /* 1 - alpha */
#define AL  0.01f       /* alpha */

// ---------------- workspace layout (floats) ----------------
#define OFF_H   0               /* Hbuf: T x H = 524288 */
#define OFF_U   524288          /* u: T = 2048 */
#define OFF_PW1 526336          /* partW1: 4 x 65536 = 262144 */
#define OFF_PB1 788480          /* partB1: 4 x 256 */
#define OFF_PW2 789504          /* partW2: 4 x 256 */
#define WS_FLOATS 790528        /* ~3 MB */

// ================= K1: forward =================
// 256 blocks x 1024 threads (4 waves/SIMD). Block owns rows [8b, 8b+8).
// Thread = (j2 = tid&127 -> cols j2, j2+128) x (kq = tid>>7 -> 32 k).
// Each ds_read_b128 of xs feeds 8 FMA (2 cols x 4 k) -> FMA-bound.
// W1: 4 dbuf batches of 16 coalesced loads; batch 0 issued pre-barrier.
__global__ __launch_bounds__(1024, 4) void fwd_kernel(
    const float* __restrict__ xs, const float* __restrict__ W1,
    const float* __restrict__ b1, const float* __restrict__ W2,
    const float* __restrict__ b2,
    float* __restrict__ Hbuf, float* __restrict__ u) {
  const int tid = threadIdx.x;
  const int j2 = tid & 127;
  const int kq = tid >> 7;              // 0..7, wave-uniform
  const int kb = kq * 32;
  const int r0 = blockIdx.x * 8;
  __shared__ __align__(16) float xsl[8 * 260];   // 8.3 KB, padded rows
  __shared__ __align__(16) float part[8 * 2048]; // 64 KB: [kq][r][j]

  if (tid < 512) {  // stage xs[8][256] -> LDS, coalesced float4
    const int row = tid >> 6;
    const int q4 = tid & 63;
    *reinterpret_cast<float4*>(&xsl[row * 260 + 4 * q4]) =
        *reinterpret_cast<const float4*>(&xs[(r0 + row) * 256 + 4 * q4]);
  }

  float wcur[16], wnxt[16];
#pragma unroll
  for (int kk = 0; kk < 8; ++kk) {      // batch 0 in flight before barrier
    wcur[2 * kk + 0] = W1[(kb + kk) * 256 + j2];
    wcur[2 * kk + 1] = W1[(kb + kk) * 256 + j2 + 128];
  }
  __syncthreads();

  float acc[16];                        // [r][c]
#pragma unroll
  for (int m = 0; m < 16; ++m) acc[m] = 0.f;
#pragma unroll
  for (int b = 0; b < 4; ++b) {
    if (b < 3) {
#pragma unroll
      for (int kk = 0; kk < 8; ++kk) {
        wnxt[2 * kk + 0] = W1[(kb + (b + 1) * 8 + kk) * 256 + j2];
        wnxt[2 * kk + 1] = W1[(kb + (b + 1) * 8 + kk) * 256 + j2 + 128];
      }
    }
    const int k = kb + b * 8;
#pragma unroll
    for (int r = 0; r < 8; ++r) {
      const float4 x0 = *reinterpret_cast<const float4*>(&xsl[r * 260 + k]);
      const float4 x1 = *reinterpret_cast<const float4*>(&xsl[r * 260 + k + 4]);
      float a0 = acc[r * 2 + 0], a1 = acc[r * 2 + 1];
      a0 = fmaf(x0.x, wcur[0], a0);  a1 = fmaf(x0.x, wcur[1], a1);
      a0 = fmaf(x0.y, wcur[2], a0);  a1 = fmaf(x0.y, wcur[3], a1);
      a0 = fmaf(x0.z, wcur[4], a0);  a1 = fmaf(x0.z, wcur[5], a1);
      a0 = fmaf(x0.w, wcur[6], a0);  a1 = fmaf(x0.w, wcur[7], a1);
      a0 = fmaf(x1.x, wcur[8], a0);  a1 = fmaf(x1.x, wcur[9], a1);
      a0 = fmaf(x1.y, wcur[10], a0); a1 = fmaf(x1.y, wcur[11], a1);
      a0 = fmaf(x1.z, wcur[12], a0); a1 = fmaf(x1.z, wcur[13], a1);
      a0 = fmaf(x1.w, wcur[14], a0); a1 = fmaf(x1.w, wcur[15], a1);
      acc[r * 2 + 0] = a0; acc[r * 2 + 1] = a1;
    }
#pragma unroll
    for (int m = 0; m < 16; ++m) wcur[m] = wnxt[m];
  }

  // ---- 8-partial combine + activation + u row-sums ----
#pragma unroll
  for (int r = 0; r < 8; ++r) {
    part[kq * 2048 + r * 256 + j2] = acc[r * 2 + 0];
    part[kq * 2048 + r * 256 + j2 + 128] = acc[r * 2 + 1];
  }
  __syncthreads();
#pragma unroll
  for (int q = 0; q < 2; ++q) {
    const int s = tid + q * 1024;       // slot = r*256 + j
    const int j = s & 255;
    float a = b1[j];
#pragma unroll
    for (int kk = 0; kk < 8; ++kk) a += part[kk * 2048 + s];
    const float h = fmaxf(a, 0.f);
    Hbuf[r0 * 256 + s] = h;             // (r0+r)*256 + j
    part[s] = h * W2[j];                // reuse kq=0 slice (own slot only)
  }
  __syncthreads();
  {
    const int r = tid >> 7;
    const int jj = tid & 127;
    part[r * 256 + jj] += part[r * 256 + jj + 128];
    __syncthreads();
    if (jj < 64) {
      float v = part[r * 256 + jj] + part[r * 256 + jj + 64];
#pragma unroll
      for (int s = 32; s >= 1; s >>= 1) v += __shfl_xor(v, s, 64);
      if (jj == 0) u[r0 + r] = v + b2[0];
    }
  }
}

// ================= K2: scan + W1/b1/W2 partials =================
// 512 blocks x 512 threads (2 blocks/CU -> 4 waves/SIMD).
// blk: tq = blk&3 (512 t), tile = blk>>2: dcb = tile>>3 (16 d), jc = tile&7 (32 j).
// Lane: jq = lane&7 (4 cols, float4 H), dh = (lane>>3)&3 (4 d's), tt2 = lane>>5;
// wave w: t-range = [w*64 + tt2*32, +32). acc = 16 regs. H: 4 dbuf batches of
// 8 float4, batch 0 issued at kernel start (hidden under the replicated scan).
__global__ __launch_bounds__(512, 4) void scan_w1_kernel(
    const float* __restrict__ u, const float* __restrict__ ys,
    const float* __restrict__ xs, const float* __restrict__ Hbuf,
    const float* __restrict__ W2,
    float* __restrict__ pW1, float* __restrict__ pB1, float* __restrict__ pW2,
    float* __restrict__ outp) {
  const int tid = threadIdx.x;
  const int blk = blockIdx.x;
  const int tq = blk & 3;
  const int tile = blk >> 2;
  const int dcb = tile >> 3;            // 0..15
  const int jc = tile & 7;              // 0..7
  const int d0 = dcb * 16;
  const int j0 = jc * 32;
  const int tb = tq * 512;
  const int lane = tid & 63;
  const int w = tid >> 6;               // 0..7
  const int jq = lane & 7;
  const int dh = (lane >> 3) & 3;
  const int tt2 = lane >> 5;
  const int tloc = w * 64 + tt2 * 32;
  const int jcol = j0 + 4 * jq;

  __shared__ __align__(16) float xt[512 * 20];  // 40 KB, pad-20 rows
  __shared__ __align__(16) float c_l[512];      // 2 KB
  __shared__ __align__(16) float red[8 * 576];  // 18 KB: [w][18][32]
  __shared__ float aggA[8], aggB[8], ag2A[8], ag2B[8], wsum[8];

  // ---- H batch 0 first into the vm queue ----
  const float* Hp = Hbuf + jcol;
  float4 hc[8], hn[8];
#pragma unroll
  for (int i = 0; i < 8; ++i)
    hc[i] = *reinterpret_cast<const float4*>(Hp + (tb + tloc + i) * 256);

  // ---- stage xs tile [512][16] with pad 20 ----
#pragma unroll
  for (int q = 0; q < 4; ++q) {
    const int idx = tid + q * 512;      // 0..2047
    const int row = idx >> 2;
    const int qd = idx & 3;
    *reinterpret_cast<float4*>(&xt[row * 20 + 4 * qd]) =
        *reinterpret_cast<const float4*>(&xs[(tb + row) * 256 + d0 + 4 * qd]);
  }

  // ---- replicated scan: thread owns t in [4*tid, 4*tid+4) ----
  float e[4], kp[4];
  {
    const float4 u4 = ((const float4*)u)[tid];
    const float uu[4] = {u4.x, u4.y, u4.z, u4.w};
#pragma unroll
    for (int q = 0; q < 2; ++q) {
      const float4 y = ((const float4*)ys)[2 * tid + q];
      const float da = y.x - uu[2 * q];
      const float db = y.z - uu[2 * q + 1];
      e[2 * q] = da * da;
      e[2 * q + 1] = db * db;
      kp[2 * q] = (y.y > 0.5f) ? 0.f : 1.f;
      kp[2 * q + 1] = (y.w > 0.5f) ? 0.f : 1.f;
    }
  }
  float A = 1.f, B = 0.f;
#pragma unroll
  for (int i = 0; i < 4; ++i) {
    const float a = kp[i] * OMA;
    B = fmaf(a, B, kp[i] * (AL * e[i]));
    A *= a;
  }
#pragma unroll
  for (int s = 1; s < 64; s <<= 1) {
    const float pA = __shfl_up(A, s, 64);
    const float pB = __shfl_up(B, s, 64);
    if (lane >= s) { B = fmaf(A, pB, B); A *= pA; }
  }
  if (lane == 63) { aggA[w] = A; aggB[w] = B; }
  __syncthreads();
  float rin;
  {
    float rw = 0.f;
    for (int v = 0; v < w; ++v) rw = fmaf(aggA[v], rw, aggB[v]);
    float lA = __shfl_up(A, 1, 64);
    float lB = __shfl_up(B, 1, 64);
    if (lane == 0) { lA = 1.f; lB = 0.f; }
    rin = fmaf(lA, rw, lB);
  }
  float sig[4];
  {
    float r = rin;
#pragma unroll
    for (int i = 0; i < 4; ++i) {
      sig[i] = e[i] - r;
      const float a = kp[i] * OMA;
      r = fmaf(a, r, kp[i] * (AL * e[i]));
    }
  }
  if (blk == 0 && tid == 511) outp[66049] = sig[3];   // sigmas[-1]

  float A2 = 1.f, B2 = 0.f;
#pragma unroll
  for (int i = 3; i >= 0; --i) {
    const float a = GL * kp[i];
    B2 = fmaf(a, B2, -sig[i]);
    A2 *= a;
  }
#pragma unroll
  for (int s = 1; s < 64; s <<= 1) {
    const float nA = __shfl_down(A2, s, 64);
    const float nB = __shfl_down(B2, s, 64);
    if (lane + s < 64) { B2 = fmaf(A2, nB, B2); A2 *= nA; }
  }
  if (lane == 0) { ag2A[w] = A2; ag2B[w] = B2; }
  __syncthreads();
  float cin;
  {
    float cw = 0.f;
    for (int v = 7; v > w; --v) cw = fmaf(ag2A[v], cw, ag2B[v]);
    float lA = __shfl_down(A2, 1, 64);
    float lB = __shfl_down(B2, 1, 64);
    if (lane == 63) { lA = 1.f; lB = 0.f; }
    cin = fmaf(lA, cw, lB);
  }
  float cr[4];
  float cc = cin, csum = 0.f;
#pragma unroll
  for (int i = 3; i >= 0; --i) {
    cc = fmaf(GL * kp[i], cc, -sig[i]);
    cr[i] = cc;
    csum += cc;
  }
  if ((tid >> 7) == tq) {               // this thread's t-range is in our slice
    const int bl = 4 * (tid - tq * 128);
    *reinterpret_cast<float4*>(&c_l[bl]) = make_float4(cr[0], cr[1], cr[2], cr[3]);
  }
  if (blk == 0) {
#pragma unroll
    for (int s = 32; s >= 1; s >>= 1) csum += __shfl_xor(csum, s, 64);
    if (lane == 0) wsum[w] = csum;
  }
  __syncthreads();                      // xt + c_l ready
  if (blk == 0 && tid == 0) {
    float s = 0.f;
#pragma unroll
    for (int v = 0; v < 8; ++v) s += wsum[v];
    outp[66048] = s;                    // total_b2
  }

  // ---- GEMM: 32 t x 4 cols x 4 d's per thread ----
  const float4 w24 = *reinterpret_cast<const float4*>(W2 + jcol);
  float acc[16];                        // [x][c], x = local d
#pragma unroll
  for (int m = 0; m < 16; ++m) acc[m] = 0.f;
  float sb[4] = {0.f, 0.f, 0.f, 0.f}, sw[4] = {0.f, 0.f, 0.f, 0.f};
  const bool do_bw = (dcb == 0);

#pragma unroll
  for (int b = 0; b < 4; ++b) {
    if (b < 3) {
#pragma unroll
      for (int i = 0; i < 8; ++i)
        hn[i] = *reinterpret_cast<const float4*>(
            Hp + (tb + tloc + (b + 1) * 8 + i) * 256);
    }
#pragma unroll
    for (int i = 0; i < 8; ++i) {
      const int row = tloc + b * 8 + i;
      const float ct = c_l[row];
      const float4 h = hc[i];
      const float gc0 = (h.x > 0.f) ? w24.x * ct : 0.f;
      const float gc1 = (h.y > 0.f) ? w24.y * ct : 0.f;
      const float gc2 = (h.z > 0.f) ? w24.z * ct : 0.f;
      const float gc3 = (h.w > 0.f) ? w24.w * ct : 0.f;
      if (do_bw) {                      // block-uniform; dh-replicated x4 (exact)
        sb[0] += gc0; sb[1] += gc1; sb[2] += gc2; sb[3] += gc3;
        sw[0] = fmaf(ct, h.x, sw[0]); sw[1] = fmaf(ct, h.y, sw[1]);
        sw[2] = fmaf(ct, h.z, sw[2]); sw[3] = fmaf(ct, h.w, sw[3]);
      }
      const float4 xv = *reinterpret_cast<const float4*>(&xt[row * 20 + dh * 4]);
      acc[0]  = fmaf(gc0, xv.x, acc[0]);
      acc[1]  = fmaf(gc1, xv.x, acc[1]);
      acc[2]  = fmaf(gc2, xv.x, acc[2]);
      acc[3]  = fmaf(gc3, xv.x, acc[3]);
      acc[4]  = fmaf(gc0, xv.y, acc[4]);
      acc[5]  = fmaf(gc1, xv.y, acc[5]);
      acc[6]  = fmaf(gc2, xv.y, acc[6]);
      acc[7]  = fmaf(gc3, xv.y, acc[7]);
      acc[8]  = fmaf(gc0, xv.z, acc[8]);
      acc[9]  = fmaf(gc1, xv.z, acc[9]);
      acc[10] = fmaf(gc2, xv.z, acc[10]);
      acc[11] = fmaf(gc3, xv.z, acc[11]);
      acc[12] = fmaf(gc0, xv.w, acc[12]);
      acc[13] = fmaf(gc1, xv.w, acc[13]);
      acc[14] = fmaf(gc2, xv.w, acc[14]);
      acc[15] = fmaf(gc3, xv.w, acc[15]);
    }
#pragma unroll
    for (int i = 0; i < 8; ++i) hc[i] = hn[i];
  }

  // ---- reduce over tt2 (shfl) then waves (LDS) ----
#pragma unroll
  for (int m = 0; m < 16; ++m) acc[m] += __shfl_xor(acc[m], 32, 64);
  if (do_bw) {
#pragma unroll
    for (int c = 0; c < 4; ++c) {       // sum over dh (x4 replicated) and tt2
      sb[c] += __shfl_xor(sb[c], 8, 64);
      sb[c] += __shfl_xor(sb[c], 16, 64);
      sb[c] += __shfl_xor(sb[c], 32, 64);
      sw[c] += __shfl_xor(sw[c], 8, 64);
      sw[c] += __shfl_xor(sw[c], 16, 64);
      sw[c] += __shfl_xor(sw[c], 32, 64);
    }
  }
  if (lane < 32) {                      // tt2 == 0 lanes
#pragma unroll
    for (int x = 0; x < 4; ++x)
      *reinterpret_cast<float4*>(&red[w * 576 + (dh * 4 + x) * 32 + jq * 4]) =
          make_float4(acc[x * 4 + 0], acc[x * 4 + 1], acc[x * 4 + 2], acc[x * 4 + 3]);
  }
  if (do_bw && lane < 8) {              // jq == lane
    *reinterpret_cast<float4*>(&red[w * 576 + 16 * 32 + lane * 4]) =
        make_float4(0.25f * sb[0], 0.25f * sb[1], 0.25f * sb[2], 0.25f * sb[3]);
    *reinterpret_cast<float4*>(&red[w * 576 + 17 * 32 + lane * 4]) =
        make_float4(0.25f * sw[0], 0.25f * sw[1], 0.25f * sw[2], 0.25f * sw[3]);
  }
  __syncthreads();
  {
    const int col = tid & 31;
    const int dd = tid >> 5;            // 0..15
    float s = 0.f;
#pragma unroll
    for (int v = 0; v < 8; ++v) s += red[v * 576 + dd * 32 + col];
    pW1[tq * 65536 + (d0 + dd) * 256 + j0 + col] = s;
  }
  if (do_bw && tid < 64) {
    const int col = tid & 31;
    const int sel = tid >> 5;           // 0 -> b1, 1 -> W2
    float s = 0.f;
#pragma unroll
    for (int v = 0; v < 8; ++v) s += red[v * 576 + (16 + sel) * 32 + col];
    (sel ? pW2 : pB1)[tq * 256 + j0 + col] = s;
  }
}

// ================= K3: deterministic reductions =================
__global__ __launch_bounds__(256) void reduce_kernel(
    const float* __restrict__ pW1, const float* __restrict__ pB1,
    const float* __restrict__ pW2, float* __restrict__ outp) {
  if (blockIdx.x < 64) {
    const int i0 = blockIdx.x * 1024 + threadIdx.x * 4;
    float4 s = make_float4(0.f, 0.f, 0.f, 0.f);
#pragma unroll
    for (int q = 0; q < 4; ++q) {
      const float4 v = *reinterpret_cast<const float4*>(pW1 + q * 65536 + i0);
      s.x += v.x; s.y += v.y; s.z += v.z; s.w += v.w;
    }
    *reinterpret_cast<float4*>(outp + i0) = s;             // total_W1
  } else {
    const int j = threadIdx.x;
    float sb = 0.f, sw = 0.f;
#pragma unroll
    for (int q = 0; q < 4; ++q) {
      sb += pB1[q * 256 + j];
      sw += pW2[q * 256 + j];
    }
    outp[65536 + j] = sb;               // total_b1
    outp[65792 + j] = sw;               // total_W2
  }
}

extern "C" void kernel_launch(void* const* d_in, const int* in_sizes, int n_in,
                              void* d_out, int out_size, void* d_ws, size_t ws_size,
                              hipStream_t stream) {
  const float* xs = (const float*)d_in[0];   // (2048, 256)
  const float* ys = (const float*)d_in[1];   // (2048, 2)
  const float* W1 = (const float*)d_in[2];   // (256, 256)
  const float* b1 = (const float*)d_in[3];   // (256,)
  const float* W2 = (const float*)d_in[4];   // (256, 1)
  const float* b2 = (const float*)d_in[5];   // (1,)
  float* outp = (float*)d_out;               // 66050 floats
  float* ws = (float*)d_ws;

  if (ws_size < (size_t)WS_FLOATS * sizeof(float)) return;  // loud fail

  float* Hbuf = ws + OFF_H;
  float* ubuf = ws + OFF_U;
  float* pW1  = ws + OFF_PW1;
  float* pB1  = ws + OFF_PB1;
  float* pW2  = ws + OFF_PW2;

  fwd_kernel<<<256, 1024, 0, stream>>>(xs, W1, b1, W2, b2, Hbuf, ubuf);
  scan_w1_kernel<<<512, 512, 0, stream>>>(ubuf, ys, xs, Hbuf, W2,
                                          pW1, pB1, pW2, outp);
  reduce_kernel<<<65, 256, 0, stream>>>(pW1, pB1, pW2, outp);
}